// Round 4
// baseline (950.840 us; speedup 1.0000x reference)
//
#include <hip/hip_runtime.h>
#include <hip/hip_bf16.h>

typedef unsigned short u16;
typedef __attribute__((ext_vector_type(8))) short short8;
typedef __attribute__((ext_vector_type(4))) float f32x4;

#define EPSV 1e-5f
#define ENC_NINF 0x007FFFFFu

__device__ __forceinline__ float bf2f(u16 u) {
    union { unsigned int i; float f; } v; v.i = ((unsigned int)u) << 16; return v.f;
}
__device__ __forceinline__ u16 f2bf(float f) {
    union { float f; unsigned int i; } v; v.f = f;
    unsigned int x = v.i;
    return (u16)((x + 0x7FFFu + ((x >> 16) & 1u)) >> 16);   // RNE
}
__device__ __forceinline__ unsigned int encbf(u16 u) {
    unsigned int f = ((unsigned int)u) << 16;
    return (f & 0x80000000u) ? ~f : (f | 0x80000000u);
}
__device__ __forceinline__ float dec(unsigned int u) {
    union { float f; unsigned int uu; } v;
    v.uu = (u & 0x80000000u) ? (u & 0x7FFFFFFFu) : ~u;
    return v.f;
}

// async 16B global -> LDS (per-lane source ok; LDS dest = uniform base + lane*16)
__device__ __forceinline__ void async16(const u16* g, u16* l) {
    __builtin_amdgcn_global_load_lds((const __attribute__((address_space(1))) void*)g,
                                     (__attribute__((address_space(3))) void*)l,
                                     16, 0, 0);
}

__global__ __launch_bounds__(256) void k_fillf(float* __restrict__ o, int n, float val)
{
    int i = blockIdx.x * 256 + threadIdx.x;
    if (i < n) o[i] = val;
}

// ---- adaptive repack: float tensors -> bf16 blob; choice -> clean int32 ----
// also initializes the fg_u/out_u encoded-max buffers (folded k_initu)
struct Ptrs { const void* p[17]; int off[18]; int chN; };

__global__ __launch_bounds__(256) void k_repack(Ptrs P, const void* __restrict__ chSrc,
                                                int* __restrict__ chi, u16* __restrict__ rp,
                                                unsigned int* __restrict__ initp, int nU)
{
    const unsigned int* probe = (const unsigned int*)P.p[9];   // w3, |x| << 2
    int cnt = 0;
#pragma unroll
    for (int i = 0; i < 64; ++i) {
        unsigned int lo = probe[i] & 0xFFFFu;
        if (((lo >> 7) & 0xFFu) >= 0x80u) ++cnt;
    }
    const bool is_f32 = (cnt > 8);

    const unsigned int* cp = (const unsigned int*)chSrc;
    int z = 0; unsigned int mx = 0;
    for (int i = 0; i < 1024; ++i) {
        unsigned int w = cp[i];
        z += (w == 0u);
        mx = (w > mx) ? w : mx;
    }
    const int chMode = (mx >= 64u) ? 2 : ((z > 300) ? 1 : 0);  // 2=f32, 1=i64, 0=i32

    const int stride = gridDim.x * 256;
    const int gid0 = blockIdx.x * 256 + threadIdx.x;

    const int totalF = P.off[17];
    for (int g = gid0; g < totalF; g += stride) {
        int t = 0;
        while (g >= P.off[t + 1]) ++t;
        int off = g - P.off[t];
        u16 v;
        if (is_f32) v = f2bf(((const float*)P.p[t])[off]);
        else        v = ((const u16*)P.p[t])[off];
        rp[g] = v;
    }
    for (int i = gid0; i < P.chN; i += stride) {
        int v;
        if (chMode == 1)      v = (int)((const long long*)chSrc)[i];
        else if (chMode == 2) v = (int)((const float*)chSrc)[i];
        else                  v = ((const int*)chSrc)[i];
        chi[i] = v & 63;
    }
    for (int i = gid0; i < nU; i += stride) initp[i] = ENC_NINF;
}

// ---- counting sort per batch: points ordered by cluster ----
__global__ __launch_bounds__(256) void k_sort(const int* __restrict__ chi,
                                              int* __restrict__ schoice,
                                              int* __restrict__ perm)
{
    __shared__ int hist[64];
    __shared__ int base[64];
    const int b = blockIdx.x, tid = threadIdx.x;
    if (tid < 64) hist[tid] = 0;
    __syncthreads();
    const int o = b << 13;
    for (int i = tid; i < 8192; i += 256) atomicAdd(&hist[chi[o + i]], 1);
    __syncthreads();
    if (tid == 0) {
        int s = 0;
        for (int k = 0; k < 64; ++k) { base[k] = s; s += hist[k]; }
    }
    __syncthreads();
    for (int i = tid; i < 8192; i += 256) {
        int k = chi[o + i];
        int pos = atomicAdd(&base[k], 1);
        schoice[o + pos] = k;
        perm[o + pos] = o + i;
    }
}

// ---- G1 (NT=2): feat = (relu(bn1(xyz.w1^T+b1))) . w2^T + b2, seg-max fused ----
__global__ __launch_bounds__(256, 2) void g1_feat(
    const u16* __restrict__ xyz, const u16* __restrict__ w1, const u16* __restrict__ b1,
    const u16* __restrict__ g1v, const u16* __restrict__ bb1,
    const u16* __restrict__ m1, const u16* __restrict__ v1,
    const u16* __restrict__ w2, const u16* __restrict__ b2,
    const int* __restrict__ schoice, const int* __restrict__ perm,
    u16* __restrict__ feat, unsigned int* __restrict__ fg_u)
{
    __shared__ __align__(16) u16 Bs[256 * 128];      // 64 KB: both w2 halves
    __shared__ unsigned int lred[8 * 256];           // 8 KB (nk <= 8 fast path)
    __shared__ float4 pw[128];
    __shared__ float xs[128], ys[128], zs[128];
    __shared__ int chs[128];
    const int tid = threadIdx.x, lane = tid & 63, wave = tid >> 6;
    const int wm = (wave & 1) << 6, wn = (wave >> 1) << 6;
    const int m0 = blockIdx.x << 7;
    if (tid < 128) {
        float s = bf2f(g1v[tid]) * rsqrtf(bf2f(v1[tid]) + EPSV);
        float4 w;
        w.x = bf2f(w1[tid * 3 + 0]) * s;
        w.y = bf2f(w1[tid * 3 + 1]) * s;
        w.z = bf2f(w1[tid * 3 + 2]) * s;
        w.w = (bf2f(b1[tid]) - bf2f(m1[tid])) * s + bf2f(bb1[tid]);
        pw[tid] = w;
        const u16* p = xyz + (size_t)perm[m0 + tid] * 3;
        xs[tid] = bf2f(p[0]); ys[tid] = bf2f(p[1]); zs[tid] = bf2f(p[2]);
        chs[tid] = schoice[m0 + tid];
    }
    const int q = lane >> 4, mr = lane & 15;
    f32x4 acc[2][4][4] = {};
#pragma unroll
    for (int i = 0; i < 16; ++i) {
        int id = (i << 8) + tid, row = id >> 4, cc = id & 15;
        async16(w2 + (size_t)row * 128 + ((cc ^ (row & 15)) << 3), &Bs[id << 3]);
    }
    __syncthreads();
    const int kmin = chs[0], nk = chs[127] - kmin + 1;
    const bool useL = (nk <= 8);
    if (useL) for (int i = tid; i < (nk << 8); i += 256) lred[i] = ENC_NINF;
#pragma unroll
    for (int kk = 0; kk < 4; ++kk) {
        const int lc = kk * 4 + q;
        float4 wv[8];
#pragma unroll
        for (int j = 0; j < 8; ++j) wv[j] = pw[kk * 32 + q * 8 + j];
        short8 af[4];
#pragma unroll
        for (int mi = 0; mi < 4; ++mi) {
            int row = wm + mi * 16 + mr;
            float x = xs[row], y = ys[row], z = zs[row];
#pragma unroll
            for (int j = 0; j < 8; ++j) {
                float val = fmaf(x, wv[j].x, fmaf(y, wv[j].y, fmaf(z, wv[j].z, wv[j].w)));
                af[mi][j] = (short)f2bf(fmaxf(val, 0.0f));
            }
        }
#pragma unroll
        for (int h = 0; h < 2; ++h) {
            short8 bfr[4];
#pragma unroll
            for (int ni = 0; ni < 4; ++ni) {
                int r = (h << 7) + wn + ni * 16 + mr;
                bfr[ni] = *(const short8*)&Bs[r * 128 + ((lc ^ (r & 15)) << 3)];
            }
#pragma unroll
            for (int mi = 0; mi < 4; ++mi)
#pragma unroll
                for (int ni = 0; ni < 4; ++ni)
                    acc[h][mi][ni] = __builtin_amdgcn_mfma_f32_16x16x32_bf16(af[mi], bfr[ni], acc[h][mi][ni], 0, 0, 0);
        }
    }
    __syncthreads();
    const int colb = lane & 15;
    const int bl = m0 >> 13;
    unsigned int* db = fg_u + (size_t)(bl << 6) * 256;
#pragma unroll
    for (int h = 0; h < 2; ++h)
#pragma unroll
        for (int ni = 0; ni < 4; ++ni) {
            int n = (h << 7) + wn + (ni << 4) + colb;
            float bv = bf2f(b2[n]);
#pragma unroll
            for (int mi = 0; mi < 4; ++mi) {
                int curk = -1; unsigned int run = 0;
#pragma unroll
                for (int r = 0; r < 4; ++r) {
                    int rr = wm + (mi << 4) + (q << 2) + r;
                    u16 vb = f2bf(acc[h][mi][ni][r] + bv);
                    feat[(size_t)(m0 + rr) * 256 + n] = vb;
                    unsigned int e = encbf(vb);
                    int k = chs[rr];
                    if (k != curk) {
                        if (curk >= 0) {
                            if (useL) atomicMax(&lred[((curk - kmin) << 8) + n], run);
                            else      atomicMax(&db[curk * 256 + n], run);
                        }
                        curk = k; run = e;
                    } else run = run > e ? run : e;
                }
                if (useL) atomicMax(&lred[((curk - kmin) << 8) + n], run);
                else      atomicMax(&db[curk * 256 + n], run);
            }
        }
    if (useL) {
        __syncthreads();
        for (int i = tid; i < (nk << 8); i += 256) {
            unsigned int v = lred[i];
            if (v != ENC_NINF) atomicMax(&db[(kmin + (i >> 8)) * 256 + (i & 255)], v);
        }
    }
}

// ---- G34: fused second_conv + out-proj + seg-max (256-thread, M=64) ----
// out = relu(bn2([fg_pts|feat].w3^T + b3)) . w4^T + b4 -> seg-max into out_u.
// MEASURED (R1-R3): only 256-thread blocks get the full ~240-reg/wave no-spill
// budget on this toolchain (g1/g3: VGPR 108-112 + 128 acc regs, 0 spill).
// 512-thread -> 128-reg cap (170 MB spill); 1024-thread -> 64 (432 MB spill),
// immovable by __launch_bounds__ 2nd arg. So: 4 waves (1M x 4N), M=64/block.
// Phase A (per 256-col half): acc_a 64 f/lane; bn2+relu -> bf16 LDS H (64x256).
// Phase B: acc_b 96 f/lane += H . w4^T, w4 staged in two 192-row chunks (24 KB).
// Peak regs ~215 < 236 proven envelope. LDS 72.3 KB -> 2 blocks/CU.
__global__ __launch_bounds__(256, 2) void g34_out(
    const int* __restrict__ schoice, const u16* __restrict__ feat,
    const u16* __restrict__ fg, const u16* __restrict__ w3, const u16* __restrict__ b3,
    const u16* __restrict__ g2, const u16* __restrict__ bb2,
    const u16* __restrict__ m2, const u16* __restrict__ v2,
    const u16* __restrict__ w4, const u16* __restrict__ b4,
    unsigned int* __restrict__ out_u)
{
    __shared__ __align__(16) u16 uni[20480];   // 40 KB: As(8K)+Bs(32K) | Bs2(24K)
    __shared__ __align__(16) u16 H[16384];     // 32 KB: h2 half 64x256 swizzled | lred
    __shared__ int chs[64];
    u16* As  = uni;
    u16* Bs  = uni + 4096;
    u16* Bs2 = uni;
    const int tid = threadIdx.x, lane = tid & 63, wave = tid >> 6;
    const int q = lane >> 4, mr = lane & 15, colb = lane & 15;
    const int m0 = blockIdx.x << 6;             // 64 rows per block
    if (tid < 64) chs[tid] = schoice[m0 + tid];
    // A staging: thread handles ids {tid, 256+tid}: rows tid>>3 and 32+(tid>>3)
    const int src_ = tid & 7;
    const u16* arow[2]; const u16* frow[2];
#pragma unroll
    for (int i = 0; i < 2; ++i) {
        int pt = m0 + (i << 5) + (tid >> 3);
        int b = pt >> 13;
        arow[i] = fg + (((b << 6) + schoice[pt]) << 8);
        frow[i] = feat + ((size_t)pt << 8);
    }
    const int scol = ((src_ ^ ((tid >> 3) & 7)) << 3);   // (row&7) same for both i
    f32x4 acc_b[4][6] = {};
    for (int nh = 0; nh < 2; ++nh) {
        // ---- phase A: h2[:, nh*256 : +256] = [fg|feat] . w3_half^T ----
        f32x4 acc_a[4][4] = {};
        for (int k0 = 0; k0 < 512; k0 += 64) {
            __syncthreads();                    // prior As/Bs (or Bs2) reads done
#pragma unroll
            for (int i = 0; i < 8; ++i) {       // w3 half: 256 rows x 64 k = 32 KB
                int id = (i << 8) + tid, row = id >> 3, cc = id & 7;
                async16(w3 + (size_t)((nh << 8) + row) * 512 + k0 + ((cc ^ (row & 7)) << 3),
                        &Bs[id << 3]);
            }
#pragma unroll
            for (int i = 0; i < 2; ++i) {       // A: 64 rows x 64 k from fg|feat
                int col = k0 + scol;
                const u16* src = (k0 < 256) ? (arow[i] + col) : (frow[i] + (col - 256));
                async16(src, &As[((i << 8) + tid) << 3]);
            }
            __syncthreads();
#pragma unroll
            for (int kk = 0; kk < 2; ++kk) {
                const int lc = (kk << 2) + q;
                short8 af[4], bfr[4];
#pragma unroll
                for (int mi = 0; mi < 4; ++mi) {
                    int r = (mi << 4) + mr;
                    af[mi] = *(const short8*)&As[r * 64 + ((lc ^ (r & 7)) << 3)];
                }
#pragma unroll
                for (int ni = 0; ni < 4; ++ni) {
                    int r = (wave << 6) + (ni << 4) + mr;
                    bfr[ni] = *(const short8*)&Bs[r * 64 + ((lc ^ (r & 7)) << 3)];
                }
#pragma unroll
                for (int mi = 0; mi < 4; ++mi)
#pragma unroll
                    for (int ni = 0; ni < 4; ++ni)
                        acc_a[mi][ni] = __builtin_amdgcn_mfma_f32_16x16x32_bf16(af[mi], bfr[ni], acc_a[mi][ni], 0, 0, 0);
            }
        }
        // ---- bn2 + relu -> H (swizzled bf16, A-operand layout) ----
        // safe: all waves passed the barriers inside the k-loop above; phase B
        // reads of the prior nh's H are long done.
#pragma unroll
        for (int ni = 0; ni < 4; ++ni) {
            int ck = (wave << 6) + (ni << 4) + colb;   // 0..255 within half
            int n = (nh << 8) + ck;
            float s = bf2f(g2[n]) * rsqrtf(bf2f(v2[n]) + EPSV);
            float t = (bf2f(b3[n]) - bf2f(m2[n])) * s + bf2f(bb2[n]);
            int cchi = ck >> 3, clo = ck & 7;
#pragma unroll
            for (int mi = 0; mi < 4; ++mi)
#pragma unroll
                for (int r = 0; r < 4; ++r) {
                    int rr = (mi << 4) + (q << 2) + r;
                    H[rr * 256 + ((cchi ^ (rr & 7)) << 3) + clo] =
                        f2bf(fmaxf(fmaf(acc_a[mi][ni][r], s, t), 0.0f));
                }
        }
        // ---- phase B: acc_b += H(64x256) . w4[:, nh*256+k0]^T, 2 row-chunks ----
        for (int k0 = 0; k0 < 256; k0 += 64) {
#pragma unroll
            for (int c = 0; c < 2; ++c) {       // w4 rows c*192..+192
                __syncthreads();                // prior Bs2/As/Bs reads done; H visible
#pragma unroll
                for (int i = 0; i < 6; ++i) {   // 192 rows x 64 k = 24 KB
                    int id = (i << 8) + tid, row = id >> 3, cc = id & 7;
                    async16(w4 + (size_t)(c * 192 + row) * 512 + (nh << 8) + k0
                                + ((cc ^ (row & 7)) << 3),
                            &Bs2[id << 3]);
                }
                __syncthreads();
#pragma unroll
                for (int kk = 0; kk < 2; ++kk) {
                    const int lc = (kk << 2) + q;
                    short8 af[4];
#pragma unroll
                    for (int mi = 0; mi < 4; ++mi) {
                        int r = (mi << 4) + mr;
                        af[mi] = *(const short8*)&H[r * 256 + (((k0 >> 3) + (lc ^ (r & 7))) << 3)];
                    }
#pragma unroll
                    for (int ni = 0; ni < 3; ++ni) {
                        int r = wave * 48 + (ni << 4) + mr;      // 0..191 in chunk
                        short8 bfr = *(const short8*)&Bs2[r * 64 + ((lc ^ (r & 7)) << 3)];
#pragma unroll
                        for (int mi = 0; mi < 4; ++mi)
                            acc_b[mi][c * 3 + ni] = __builtin_amdgcn_mfma_f32_16x16x32_bf16(af[mi], bfr, acc_b[mi][c * 3 + ni], 0, 0, 0);
                    }
                }
            }
        }
    }
    // ---- fused seg-max epilogue ----
    __syncthreads();                             // all H reads done; reuse H as lred
    unsigned int* lred = (unsigned int*)H;       // 8192 u32 capacity
    const int kmin = chs[0], nk = chs[63] - kmin + 1;
    const bool useL = (nk <= 21);                // nk*384*4 <= 32 KB
    const int bl = m0 >> 13;
    unsigned int* db = out_u + (size_t)(bl << 6) * 384;
    if (useL) for (int i = tid; i < nk * 384; i += 256) lred[i] = ENC_NINF;
    __syncthreads();
#pragma unroll
    for (int j = 0; j < 6; ++j) {
        const int c = j >> 1 >= 1 ? (j >= 3 ? 1 : 0) : 0;        // j<3 -> c=0, else 1
        const int ni = (j < 3) ? j : (j - 3);
        int nc = (j < 3 ? 0 : 192) + wave * 48 + (ni << 4) + colb;
        float bv = bf2f(b4[nc]);
#pragma unroll
        for (int mi = 0; mi < 4; ++mi) {
            int curk = -1; unsigned int run = 0;
#pragma unroll
            for (int r = 0; r < 4; ++r) {
                int rr = (mi << 4) + (q << 2) + r;
                unsigned int e = encbf(f2bf(acc_b[mi][j][r] + bv));
                int k = chs[rr];
                if (k != curk) {
                    if (curk >= 0) {
                        if (useL) atomicMax(&lred[(curk - kmin) * 384 + nc], run);
                        else      atomicMax(&db[curk * 384 + nc], run);
                    }
                    curk = k; run = e;
                } else run = run > e ? run : e;
            }
            if (useL) atomicMax(&lred[(curk - kmin) * 384 + nc], run);
            else      atomicMax(&db[curk * 384 + nc], run);
        }
    }
    if (useL) {
        __syncthreads();
        for (int i = tid; i < nk * 384; i += 256) {
            unsigned int v = lred[i];
            if (v != ENC_NINF) {
                int kq = i / 384;
                atomicMax(&db[(kmin + kq) * 384 + (i - kq * 384)], v);
            }
        }
    }
}

__global__ __launch_bounds__(256) void k_dec_bf(const unsigned int* __restrict__ u,
                                                u16* __restrict__ o, int n)
{
    int i = blockIdx.x * 256 + threadIdx.x;
    if (i < n) o[i] = f2bf(dec(u[i]));
}
__global__ __launch_bounds__(256) void k_dec_f32(const unsigned int* __restrict__ u,
                                                 float* __restrict__ o, int n)
{
    int i = blockIdx.x * 256 + threadIdx.x;
    if (i < n) o[i] = dec(u[i]);
}

extern "C" void kernel_launch(void* const* d_in, const int* in_sizes, int n_in,
                              void* d_out, int out_size, void* d_ws, size_t ws_size,
                              hipStream_t stream)
{
    float* out = (float*)d_out;
    if (n_in != 18) {
        k_fillf<<<dim3((out_size + 255) / 256), 256, 0, stream>>>(out, out_size, 1000.0f);
        return;
    }

    const int map[17] = {0, 2, 3, 4, 5, 6, 7, 8, 9, 10, 11, 12, 13, 14, 15, 16, 17};
    Ptrs P;
    P.off[0] = 0;
    for (int i = 0; i < 17; ++i) {
        P.p[i] = d_in[map[i]];
        P.off[i + 1] = P.off[i] + in_sizes[map[i]];
    }
    P.chN = in_sizes[1];

    char* ws = (char*)d_ws;
    int* chi = (int*)ws;
    const size_t chiB = ((size_t)P.chN * 4 + 255) & ~255ull;
    int* schoice = (int*)(ws + chiB);
    int* perm    = (int*)(ws + 2 * chiB);
    u16* rp = (u16*)(ws + 3 * chiB);
    const size_t rpB = ((size_t)P.off[17] * 2 + 255) & ~255ull;
    const size_t RPB = 3 * chiB + rpB;

    // fixed region: fg_u (32*64*256 u32) + out_u (32*64*384 u32) = 5,242,880 B
    unsigned int* fg_u_all  = (unsigned int*)(ws + RPB);
    unsigned int* out_u_all = fg_u_all + 32 * 64 * 256;
    const size_t UB = 5242880ull;
    const int nU = 32 * 64 * 640;

    k_repack<<<dim3(1024), 256, 0, stream>>>(P, d_in[1], chi, rp, fg_u_all, nU);
    k_sort<<<dim3(P.chN >> 13), 256, 0, stream>>>(chi, schoice, perm);

    const u16* xyz  = rp + P.off[0];
    const u16* w1   = rp + P.off[1];
    const u16* b1   = rp + P.off[2];
    const u16* bn1g = rp + P.off[3];
    const u16* bn1b = rp + P.off[4];
    const u16* bn1m = rp + P.off[5];
    const u16* bn1v = rp + P.off[6];
    const u16* w2   = rp + P.off[7];
    const u16* b2   = rp + P.off[8];
    const u16* w3   = rp + P.off[9];
    const u16* b3   = rp + P.off[10];
    const u16* bn2g = rp + P.off[11];
    const u16* bn2b = rp + P.off[12];
    const u16* bn2m = rp + P.off[13];
    const u16* bn2v = rp + P.off[14];
    const u16* w4   = rp + P.off[15];
    const u16* b4   = rp + P.off[16];

    // per-batch: feat 4,194,304 + fg 32,768 = 4,227,072  (h2 eliminated by fusion)
    const size_t PB = 4227072ull;
    int sb = 32;
    while (sb > 1 && RPB + UB + (size_t)sb * PB > ws_size) sb >>= 1;
    if (RPB + UB + PB > ws_size) {
        k_fillf<<<dim3((out_size + 255) / 256), 256, 0, stream>>>(out, out_size, 3000.0f);
        return;
    }
    const int ns = 32 / sb;

    char* wsb = ws + RPB + UB;
    const size_t featB = (size_t)sb * 8192 * 256 * 2;
    u16* feat = (u16*)(wsb);
    u16* fg   = (u16*)(wsb + featB);

    const int mblk  = sb << 6;       // 128-row M-tiles (g1)
    const int mblk2 = sb << 7;       // 64-row M-tiles (g34)
    const int nfg = sb * 64 * 256;
    const int nou = sb * 64 * 384;
    for (int s = 0; s < ns; ++s) {
        const int b0 = s * sb;
        const int pt0 = b0 << 13;
        const int* sch_sl = schoice + pt0;
        const int* perm_sl = perm + pt0;
        unsigned int* fg_u  = fg_u_all + (size_t)b0 * 64 * 256;
        unsigned int* out_u = out_u_all + (size_t)b0 * 64 * 384;
        g1_feat<<<dim3(mblk), 256, 0, stream>>>(xyz, w1, b1, bn1g, bn1b, bn1m, bn1v,
                                                w2, b2, sch_sl, perm_sl, feat, fg_u);
        k_dec_bf<<<dim3((nfg + 255) / 256), 256, 0, stream>>>(fg_u, fg, nfg);
        g34_out<<<dim3(mblk2), 256, 0, stream>>>(sch_sl, feat, fg, w3, b3,
                                                 bn2g, bn2b, bn2m, bn2v, w4, b4, out_u);
        k_dec_f32<<<dim3((nou + 255) / 256), 256, 0, stream>>>(out_u,
                                                               out + ((size_t)b0 << 6) * 384, nou);
    }
}

// Round 5
// 550.750 us; speedup vs baseline: 1.7264x; 1.7264x over previous
//
#include <hip/hip_runtime.h>
#include <hip/hip_bf16.h>

typedef unsigned short u16;
typedef __attribute__((ext_vector_type(8))) short short8;
typedef __attribute__((ext_vector_type(4))) float f32x4;

#define EPSV 1e-5f
#define ENC_NINF 0x007FFFFFu

__device__ __forceinline__ float bf2f(u16 u) {
    union { unsigned int i; float f; } v; v.i = ((unsigned int)u) << 16; return v.f;
}
__device__ __forceinline__ u16 f2bf(float f) {
    union { float f; unsigned int i; } v; v.f = f;
    unsigned int x = v.i;
    return (u16)((x + 0x7FFFu + ((x >> 16) & 1u)) >> 16);   // RNE
}
__device__ __forceinline__ unsigned int encbf(u16 u) {
    unsigned int f = ((unsigned int)u) << 16;
    return (f & 0x80000000u) ? ~f : (f | 0x80000000u);
}
__device__ __forceinline__ float dec(unsigned int u) {
    union { float f; unsigned int uu; } v;
    v.uu = (u & 0x80000000u) ? (u & 0x7FFFFFFFu) : ~u;
    return v.f;
}

// async 16B global -> LDS (per-lane source ok; LDS dest = uniform base + lane*16)
__device__ __forceinline__ void async16(const u16* g, u16* l) {
    __builtin_amdgcn_global_load_lds((const __attribute__((address_space(1))) void*)g,
                                     (__attribute__((address_space(3))) void*)l,
                                     16, 0, 0);
}

__global__ __launch_bounds__(256) void k_fillf(float* __restrict__ o, int n, float val)
{
    int i = blockIdx.x * 256 + threadIdx.x;
    if (i < n) o[i] = val;
}

// ---- adaptive repack: float tensors -> bf16 blob; choice -> clean int32 ----
// also initializes the fg_u/out_u encoded-max buffers (folded k_initu)
struct Ptrs { const void* p[17]; int off[18]; int chN; };

__global__ __launch_bounds__(256) void k_repack(Ptrs P, const void* __restrict__ chSrc,
                                                int* __restrict__ chi, u16* __restrict__ rp,
                                                unsigned int* __restrict__ initp, int nU)
{
    const unsigned int* probe = (const unsigned int*)P.p[9];   // w3, |x| << 2
    int cnt = 0;
#pragma unroll
    for (int i = 0; i < 64; ++i) {
        unsigned int lo = probe[i] & 0xFFFFu;
        if (((lo >> 7) & 0xFFu) >= 0x80u) ++cnt;
    }
    const bool is_f32 = (cnt > 8);

    const unsigned int* cp = (const unsigned int*)chSrc;
    int z = 0; unsigned int mx = 0;
    for (int i = 0; i < 1024; ++i) {
        unsigned int w = cp[i];
        z += (w == 0u);
        mx = (w > mx) ? w : mx;
    }
    const int chMode = (mx >= 64u) ? 2 : ((z > 300) ? 1 : 0);  // 2=f32, 1=i64, 0=i32

    const int stride = gridDim.x * 256;
    const int gid0 = blockIdx.x * 256 + threadIdx.x;

    const int totalF = P.off[17];
    for (int g = gid0; g < totalF; g += stride) {
        int t = 0;
        while (g >= P.off[t + 1]) ++t;
        int off = g - P.off[t];
        u16 v;
        if (is_f32) v = f2bf(((const float*)P.p[t])[off]);
        else        v = ((const u16*)P.p[t])[off];
        rp[g] = v;
    }
    for (int i = gid0; i < P.chN; i += stride) {
        int v;
        if (chMode == 1)      v = (int)((const long long*)chSrc)[i];
        else if (chMode == 2) v = (int)((const float*)chSrc)[i];
        else                  v = ((const int*)chSrc)[i];
        chi[i] = v & 63;
    }
    for (int i = gid0; i < nU; i += stride) initp[i] = ENC_NINF;
}

// ---- counting sort per batch: points ordered by cluster ----
__global__ __launch_bounds__(256) void k_sort(const int* __restrict__ chi,
                                              int* __restrict__ schoice,
                                              int* __restrict__ perm)
{
    __shared__ int hist[64];
    __shared__ int base[64];
    const int b = blockIdx.x, tid = threadIdx.x;
    if (tid < 64) hist[tid] = 0;
    __syncthreads();
    const int o = b << 13;
    for (int i = tid; i < 8192; i += 256) atomicAdd(&hist[chi[o + i]], 1);
    __syncthreads();
    if (tid == 0) {
        int s = 0;
        for (int k = 0; k < 64; ++k) { base[k] = s; s += hist[k]; }
    }
    __syncthreads();
    for (int i = tid; i < 8192; i += 256) {
        int k = chi[o + i];
        int pos = atomicAdd(&base[k], 1);
        schoice[o + pos] = k;
        perm[o + pos] = o + i;
    }
}

// ---- G1 (NT=2): feat = (relu(bn1(xyz.w1^T+b1))) . w2^T + b2, seg-max fused ----
__global__ __launch_bounds__(256, 2) void g1_feat(
    const u16* __restrict__ xyz, const u16* __restrict__ w1, const u16* __restrict__ b1,
    const u16* __restrict__ g1v, const u16* __restrict__ bb1,
    const u16* __restrict__ m1, const u16* __restrict__ v1,
    const u16* __restrict__ w2, const u16* __restrict__ b2,
    const int* __restrict__ schoice, const int* __restrict__ perm,
    u16* __restrict__ feat, unsigned int* __restrict__ fg_u)
{
    __shared__ __align__(16) u16 Bs[256 * 128];      // 64 KB: both w2 halves
    __shared__ unsigned int lred[8 * 256];           // 8 KB (nk <= 8 fast path)
    __shared__ float4 pw[128];
    __shared__ float xs[128], ys[128], zs[128];
    __shared__ int chs[128];
    const int tid = threadIdx.x, lane = tid & 63, wave = tid >> 6;
    const int wm = (wave & 1) << 6, wn = (wave >> 1) << 6;
    const int m0 = blockIdx.x << 7;
    if (tid < 128) {
        float s = bf2f(g1v[tid]) * rsqrtf(bf2f(v1[tid]) + EPSV);
        float4 w;
        w.x = bf2f(w1[tid * 3 + 0]) * s;
        w.y = bf2f(w1[tid * 3 + 1]) * s;
        w.z = bf2f(w1[tid * 3 + 2]) * s;
        w.w = (bf2f(b1[tid]) - bf2f(m1[tid])) * s + bf2f(bb1[tid]);
        pw[tid] = w;
        const u16* p = xyz + (size_t)perm[m0 + tid] * 3;
        xs[tid] = bf2f(p[0]); ys[tid] = bf2f(p[1]); zs[tid] = bf2f(p[2]);
        chs[tid] = schoice[m0 + tid];
    }
    const int q = lane >> 4, mr = lane & 15;
    f32x4 acc[2][4][4] = {};
#pragma unroll
    for (int i = 0; i < 16; ++i) {
        int id = (i << 8) + tid, row = id >> 4, cc = id & 15;
        async16(w2 + (size_t)row * 128 + ((cc ^ (row & 15)) << 3), &Bs[id << 3]);
    }
    __syncthreads();
    const int kmin = chs[0], nk = chs[127] - kmin + 1;
    const bool useL = (nk <= 8);
    if (useL) for (int i = tid; i < (nk << 8); i += 256) lred[i] = ENC_NINF;
#pragma unroll
    for (int kk = 0; kk < 4; ++kk) {
        const int lc = kk * 4 + q;
        float4 wv[8];
#pragma unroll
        for (int j = 0; j < 8; ++j) wv[j] = pw[kk * 32 + q * 8 + j];
        short8 af[4];
#pragma unroll
        for (int mi = 0; mi < 4; ++mi) {
            int row = wm + mi * 16 + mr;
            float x = xs[row], y = ys[row], z = zs[row];
#pragma unroll
            for (int j = 0; j < 8; ++j) {
                float val = fmaf(x, wv[j].x, fmaf(y, wv[j].y, fmaf(z, wv[j].z, wv[j].w)));
                af[mi][j] = (short)f2bf(fmaxf(val, 0.0f));
            }
        }
#pragma unroll
        for (int h = 0; h < 2; ++h) {
            short8 bfr[4];
#pragma unroll
            for (int ni = 0; ni < 4; ++ni) {
                int r = (h << 7) + wn + ni * 16 + mr;
                bfr[ni] = *(const short8*)&Bs[r * 128 + ((lc ^ (r & 15)) << 3)];
            }
#pragma unroll
            for (int mi = 0; mi < 4; ++mi)
#pragma unroll
                for (int ni = 0; ni < 4; ++ni)
                    acc[h][mi][ni] = __builtin_amdgcn_mfma_f32_16x16x32_bf16(af[mi], bfr[ni], acc[h][mi][ni], 0, 0, 0);
        }
    }
    __syncthreads();
    const int colb = lane & 15;
    const int bl = m0 >> 13;
    unsigned int* db = fg_u + (size_t)(bl << 6) * 256;
#pragma unroll
    for (int h = 0; h < 2; ++h)
#pragma unroll
        for (int ni = 0; ni < 4; ++ni) {
            int n = (h << 7) + wn + (ni << 4) + colb;
            float bv = bf2f(b2[n]);
#pragma unroll
            for (int mi = 0; mi < 4; ++mi) {
                int curk = -1; unsigned int run = 0;
#pragma unroll
                for (int r = 0; r < 4; ++r) {
                    int rr = wm + (mi << 4) + (q << 2) + r;
                    u16 vb = f2bf(acc[h][mi][ni][r] + bv);
                    feat[(size_t)(m0 + rr) * 256 + n] = vb;
                    unsigned int e = encbf(vb);
                    int k = chs[rr];
                    if (k != curk) {
                        if (curk >= 0) {
                            if (useL) atomicMax(&lred[((curk - kmin) << 8) + n], run);
                            else      atomicMax(&db[curk * 256 + n], run);
                        }
                        curk = k; run = e;
                    } else run = run > e ? run : e;
                }
                if (useL) atomicMax(&lred[((curk - kmin) << 8) + n], run);
                else      atomicMax(&db[curk * 256 + n], run);
            }
        }
    if (useL) {
        __syncthreads();
        for (int i = tid; i < (nk << 8); i += 256) {
            unsigned int v = lred[i];
            if (v != ENC_NINF) atomicMax(&db[(kmin + (i >> 8)) * 256 + (i & 255)], v);
        }
    }
}

// ---- G3: h2 = relu(bn2([fg_pts|feat] . w3^T + b3)), NT=2, BK=64 (baseline form,
// proven: VGPR 108 + 128 AGPR acc = 236 total, 0 spill, 0 bank conflicts) ----
__global__ __launch_bounds__(256, 2) void g3_h2(
    const int* __restrict__ schoice, const u16* __restrict__ feat,
    const u16* __restrict__ fg, const u16* __restrict__ w3, const u16* __restrict__ b3,
    const u16* __restrict__ g2, const u16* __restrict__ bb2,
    const u16* __restrict__ m2, const u16* __restrict__ v2,
    u16* __restrict__ h2)
{
    __shared__ __align__(16) u16 As[128 * 64];
    __shared__ __align__(16) u16 Bs[2 * 128 * 64];
    const int tid = threadIdx.x, lane = tid & 63, wave = tid >> 6;
    const int wm = (wave & 1) << 6, wn = (wave >> 1) << 6;
    const int m0 = blockIdx.x << 7, n0 = blockIdx.y << 8;   // 256-wide N group
    const int c = tid & 7, rb = tid >> 3;
    const u16* fgrow[4]; const u16* ftrow[4];
#pragma unroll
    for (int i = 0; i < 4; ++i) {
        int pt = m0 + rb + (i << 5);
        int b = pt >> 13;
        fgrow[i] = fg + (((b << 6) + schoice[pt]) << 8);
        ftrow[i] = feat + ((size_t)pt << 8);
    }
    f32x4 acc[2][4][4] = {};
    for (int k0 = 0; k0 < 512; k0 += 64) {
        __syncthreads();
#pragma unroll
        for (int nt = 0; nt < 2; ++nt)
#pragma unroll
            for (int i = 0; i < 4; ++i) {
                int id = (i << 8) + tid, row = id >> 3, cc = id & 7;
                async16(w3 + (size_t)(n0 + nt * 128 + row) * 512 + k0 + ((cc ^ (row & 7)) << 3),
                        &Bs[nt * 8192 + (id << 3)]);
            }
#pragma unroll
        for (int i = 0; i < 4; ++i) {
            int r = rb + (i << 5);
            int col = k0 + ((c ^ (r & 7)) << 3);
            const u16* src = (col < 256) ? (fgrow[i] + col) : (ftrow[i] + (col - 256));
            async16(src, &As[(((i << 8) + tid) << 3)]);
        }
        __syncthreads();
        const int q = lane >> 4, mr = lane & 15;
#pragma unroll
        for (int kk = 0; kk < 2; ++kk) {
            short8 af[4];
            const int lc = kk * 4 + q;
#pragma unroll
            for (int mi = 0; mi < 4; ++mi) {
                int r = wm + mi * 16 + mr;
                af[mi] = *(const short8*)&As[r * 64 + ((lc ^ (r & 7)) << 3)];
            }
#pragma unroll
            for (int nt = 0; nt < 2; ++nt) {
                short8 bfr[4];
#pragma unroll
                for (int ni = 0; ni < 4; ++ni) {
                    int r = wn + ni * 16 + mr;
                    bfr[ni] = *(const short8*)&Bs[nt * 8192 + r * 64 + ((lc ^ (r & 7)) << 3)];
                }
#pragma unroll
                for (int mi = 0; mi < 4; ++mi)
#pragma unroll
                    for (int ni = 0; ni < 4; ++ni)
                        acc[nt][mi][ni] = __builtin_amdgcn_mfma_f32_16x16x32_bf16(af[mi], bfr[ni], acc[nt][mi][ni], 0, 0, 0);
            }
        }
    }
    const int q = lane >> 4, colb = lane & 15;
#pragma unroll
    for (int nt = 0; nt < 2; ++nt)
#pragma unroll
        for (int ni = 0; ni < 4; ++ni) {
            int n = n0 + nt * 128 + wn + (ni << 4) + colb;
            float s = bf2f(g2[n]) * rsqrtf(bf2f(v2[n]) + EPSV);
            float t = (bf2f(b3[n]) - bf2f(m2[n])) * s + bf2f(bb2[n]);
#pragma unroll
            for (int mi = 0; mi < 4; ++mi)
#pragma unroll
                for (int r = 0; r < 4; ++r) {
                    int m = m0 + wm + (mi << 4) + (q << 2) + r;
                    h2[(size_t)m * 512 + n] = f2bf(fmaxf(fmaf(acc[nt][mi][ni][r], s, t), 0.0f));
                }
        }
}

// ---- G4: out = h2 . w4^T + b4, M=64, FULL N=384 in one pass, seg-max fused ----
// Baseline g4 ran grid (M,3): every N-slice re-read all of h2 -> 3x268 MB = 804 MB.
// This form reads h2 ONCE (268 MB): one block owns 64 rows x all 384 cols.
// Register budget (R1-R4 lesson: acc lives in AGPRs, unified 512-file, and the
// 2-waves/SIMD envelope caps VGPR+AGPR at 256): acc 96 AGPR + ~110 VGPR = 206. OK.
// LDS: As 8 KB + Bs 48 KB = 56 KB -> 2 blocks/CU.
__global__ __launch_bounds__(256, 2) void g4_out(
    const u16* __restrict__ A, const u16* __restrict__ w4,
    const u16* __restrict__ bias, const int* __restrict__ schoice,
    unsigned int* __restrict__ out_u)
{
    __shared__ __align__(16) u16 smem[28672];        // 56 KB: As(8K) + Bs(48K)
    __shared__ int chs[64];
    u16* As = smem;
    u16* Bs = smem + 4096;
    const int tid = threadIdx.x, lane = tid & 63, wave = tid >> 6;
    const int m0 = blockIdx.x << 6;
    if (tid < 64) chs[tid] = schoice[m0 + tid];
    f32x4 acc[4][6] = {};
    for (int k0 = 0; k0 < 512; k0 += 64) {
        __syncthreads();
#pragma unroll
        for (int i = 0; i < 12; ++i) {               // w4: 384 rows x 64 k
            int id = (i << 8) + tid, row = id >> 3, cc = id & 7;
            async16(w4 + (size_t)row * 512 + k0 + ((cc ^ (row & 7)) << 3),
                    &Bs[id << 3]);
        }
#pragma unroll
        for (int i = 0; i < 2; ++i) {                // h2: 64 rows x 64 k
            int id = (i << 8) + tid, row = id >> 3, cc = id & 7;
            async16(A + (size_t)(m0 + row) * 512 + k0 + ((cc ^ (row & 7)) << 3),
                    &As[id << 3]);
        }
        __syncthreads();
        const int q = lane >> 4, mr = lane & 15;
#pragma unroll
        for (int kk = 0; kk < 2; ++kk) {
            const int lc = (kk << 2) + q;
            short8 af[4];
#pragma unroll
            for (int mi = 0; mi < 4; ++mi) {
                int r = (mi << 4) + mr;
                af[mi] = *(const short8*)&As[r * 64 + ((lc ^ (r & 7)) << 3)];
            }
#pragma unroll
            for (int ni = 0; ni < 6; ++ni) {
                int r = wave * 96 + (ni << 4) + mr;
                short8 bfr = *(const short8*)&Bs[r * 64 + ((lc ^ (r & 7)) << 3)];
#pragma unroll
                for (int mi = 0; mi < 4; ++mi)
                    acc[mi][ni] = __builtin_amdgcn_mfma_f32_16x16x32_bf16(af[mi], bfr, acc[mi][ni], 0, 0, 0);
            }
        }
    }
    // ---- fused seg-max epilogue ----
    __syncthreads();                                 // staging reads done; reuse smem
    unsigned int* lred = (unsigned int*)smem;        // 14336 u32 capacity
    const int kmin = chs[0], nk = chs[63] - kmin + 1;
    const bool useL = (nk <= 37);                    // nk*384*4 <= 56 KB
    const int bl = m0 >> 13;
    unsigned int* db = out_u + (size_t)(bl << 6) * 384;
    if (useL) for (int i = tid; i < nk * 384; i += 256) lred[i] = ENC_NINF;
    __syncthreads();
    const int q = lane >> 4, colb = lane & 15;
#pragma unroll
    for (int ni = 0; ni < 6; ++ni) {
        int nc = wave * 96 + (ni << 4) + colb;
        float bv = bf2f(bias[nc]);
#pragma unroll
        for (int mi = 0; mi < 4; ++mi) {
            int curk = -1; unsigned int run = 0;
#pragma unroll
            for (int r = 0; r < 4; ++r) {
                int rr = (mi << 4) + (q << 2) + r;
                unsigned int e = encbf(f2bf(acc[mi][ni][r] + bv));
                int k = chs[rr];
                if (k != curk) {
                    if (curk >= 0) {
                        if (useL) atomicMax(&lred[(curk - kmin) * 384 + nc], run);
                        else      atomicMax(&db[curk * 384 + nc], run);
                    }
                    curk = k; run = e;
                } else run = run > e ? run : e;
            }
            if (useL) atomicMax(&lred[(curk - kmin) * 384 + nc], run);
            else      atomicMax(&db[curk * 384 + nc], run);
        }
    }
    if (useL) {
        __syncthreads();
        for (int i = tid; i < nk * 384; i += 256) {
            unsigned int v = lred[i];
            if (v != ENC_NINF) {
                int kq = i / 384;
                atomicMax(&db[(kmin + kq) * 384 + (i - kq * 384)], v);
            }
        }
    }
}

__global__ __launch_bounds__(256) void k_dec_bf(const unsigned int* __restrict__ u,
                                                u16* __restrict__ o, int n)
{
    int i = blockIdx.x * 256 + threadIdx.x;
    if (i < n) o[i] = f2bf(dec(u[i]));
}
__global__ __launch_bounds__(256) void k_dec_f32(const unsigned int* __restrict__ u,
                                                 float* __restrict__ o, int n)
{
    int i = blockIdx.x * 256 + threadIdx.x;
    if (i < n) o[i] = dec(u[i]);
}

extern "C" void kernel_launch(void* const* d_in, const int* in_sizes, int n_in,
                              void* d_out, int out_size, void* d_ws, size_t ws_size,
                              hipStream_t stream)
{
    float* out = (float*)d_out;
    if (n_in != 18) {
        k_fillf<<<dim3((out_size + 255) / 256), 256, 0, stream>>>(out, out_size, 1000.0f);
        return;
    }

    const int map[17] = {0, 2, 3, 4, 5, 6, 7, 8, 9, 10, 11, 12, 13, 14, 15, 16, 17};
    Ptrs P;
    P.off[0] = 0;
    for (int i = 0; i < 17; ++i) {
        P.p[i] = d_in[map[i]];
        P.off[i + 1] = P.off[i] + in_sizes[map[i]];
    }
    P.chN = in_sizes[1];

    char* ws = (char*)d_ws;
    int* chi = (int*)ws;
    const size_t chiB = ((size_t)P.chN * 4 + 255) & ~255ull;
    int* schoice = (int*)(ws + chiB);
    int* perm    = (int*)(ws + 2 * chiB);
    u16* rp = (u16*)(ws + 3 * chiB);
    const size_t rpB = ((size_t)P.off[17] * 2 + 255) & ~255ull;
    const size_t RPB = 3 * chiB + rpB;

    // fixed region: fg_u (32*64*256 u32) + out_u (32*64*384 u32) = 5,242,880 B
    unsigned int* fg_u_all  = (unsigned int*)(ws + RPB);
    unsigned int* out_u_all = fg_u_all + 32 * 64 * 256;
    const size_t UB = 5242880ull;
    const int nU = 32 * 64 * 640;

    k_repack<<<dim3(1024), 256, 0, stream>>>(P, d_in[1], chi, rp, fg_u_all, nU);
    k_sort<<<dim3(P.chN >> 13), 256, 0, stream>>>(chi, schoice, perm);

    const u16* xyz  = rp + P.off[0];
    const u16* w1   = rp + P.off[1];
    const u16* b1   = rp + P.off[2];
    const u16* bn1g = rp + P.off[3];
    const u16* bn1b = rp + P.off[4];
    const u16* bn1m = rp + P.off[5];
    const u16* bn1v = rp + P.off[6];
    const u16* w2   = rp + P.off[7];
    const u16* b2   = rp + P.off[8];
    const u16* w3   = rp + P.off[9];
    const u16* b3   = rp + P.off[10];
    const u16* bn2g = rp + P.off[11];
    const u16* bn2b = rp + P.off[12];
    const u16* bn2m = rp + P.off[13];
    const u16* bn2v = rp + P.off[14];
    const u16* w4   = rp + P.off[15];
    const u16* b4   = rp + P.off[16];

    // per-batch: feat 4,194,304 + h2 8,388,608 + fg 32,768 = 12,615,680
    const size_t PB = 12615680ull;
    int sb = 32;
    while (sb > 1 && RPB + UB + (size_t)sb * PB > ws_size) sb >>= 1;
    if (RPB + UB + PB > ws_size) {
        k_fillf<<<dim3((out_size + 255) / 256), 256, 0, stream>>>(out, out_size, 3000.0f);
        return;
    }
    const int ns = 32 / sb;

    char* wsb = ws + RPB + UB;
    const size_t featB = (size_t)sb * 8192 * 256 * 2;
    const size_t h2B   = (size_t)sb * 8192 * 512 * 2;
    u16* feat = (u16*)(wsb);
    u16* h2s  = (u16*)(wsb + featB);
    u16* fg   = (u16*)(wsb + featB + h2B);

    const int mblk  = sb << 6;       // 128-row M-tiles (g1, g3)
    const int mblk2 = sb << 7;       // 64-row M-tiles (g4)
    const int nfg = sb * 64 * 256;
    const int nou = sb * 64 * 384;
    for (int s = 0; s < ns; ++s) {
        const int b0 = s * sb;
        const int pt0 = b0 << 13;
        const int* sch_sl = schoice + pt0;
        const int* perm_sl = perm + pt0;
        unsigned int* fg_u  = fg_u_all + (size_t)b0 * 64 * 256;
        unsigned int* out_u = out_u_all + (size_t)b0 * 64 * 384;
        g1_feat<<<dim3(mblk), 256, 0, stream>>>(xyz, w1, b1, bn1g, bn1b, bn1m, bn1v,
                                                w2, b2, sch_sl, perm_sl, feat, fg_u);
        k_dec_bf<<<dim3((nfg + 255) / 256), 256, 0, stream>>>(fg_u, fg, nfg);
        g3_h2<<<dim3(mblk, 2), 256, 0, stream>>>(sch_sl, feat, fg, w3, b3,
                                                 bn2g, bn2b, bn2m, bn2v, h2s);
        g4_out<<<dim3(mblk2), 256, 0, stream>>>(h2s, w4, b4, sch_sl, out_u);
        k_dec_f32<<<dim3((nou + 255) / 256), 256, 0, stream>>>(out_u,
                                                               out + ((size_t)b0 << 6) * 384, nou);
    }
}

// Round 6
// 543.416 us; speedup vs baseline: 1.7497x; 1.0135x over previous
//
#include <hip/hip_runtime.h>
#include <hip/hip_bf16.h>

typedef unsigned short u16;
typedef __attribute__((ext_vector_type(8))) short short8;
typedef __attribute__((ext_vector_type(4))) float f32x4;

#define EPSV 1e-5f
#define ENC_NINF 0x007FFFFFu

__device__ __forceinline__ float bf2f(u16 u) {
    union { unsigned int i; float f; } v; v.i = ((unsigned int)u) << 16; return v.f;
}
__device__ __forceinline__ u16 f2bf(float f) {
    union { float f; unsigned int i; } v; v.f = f;
    unsigned int x = v.i;
    return (u16)((x + 0x7FFFu + ((x >> 16) & 1u)) >> 16);   // RNE
}
__device__ __forceinline__ unsigned int encbf(u16 u) {
    unsigned int f = ((unsigned int)u) << 16;
    return (f & 0x80000000u) ? ~f : (f | 0x80000000u);
}
__device__ __forceinline__ float dec(unsigned int u) {
    union { float f; unsigned int uu; } v;
    v.uu = (u & 0x80000000u) ? (u & 0x7FFFFFFFu) : ~u;
    return v.f;
}

// async 16B global -> LDS (per-lane source ok; LDS dest = uniform base + lane*16)
__device__ __forceinline__ void async16(const u16* g, u16* l) {
    __builtin_amdgcn_global_load_lds((const __attribute__((address_space(1))) void*)g,
                                     (__attribute__((address_space(3))) void*)l,
                                     16, 0, 0);
}

__global__ __launch_bounds__(256) void k_fillf(float* __restrict__ o, int n, float val)
{
    int i = blockIdx.x * 256 + threadIdx.x;
    if (i < n) o[i] = val;
}

// ---- adaptive repack: float tensors -> bf16 blob; choice -> clean int32 ----
// also initializes the fg_u/out_u encoded-max buffers (folded k_initu)
struct Ptrs { const void* p[17]; int off[18]; int chN; };

__global__ __launch_bounds__(256) void k_repack(Ptrs P, const void* __restrict__ chSrc,
                                                int* __restrict__ chi, u16* __restrict__ rp,
                                                unsigned int* __restrict__ initp, int nU)
{
    const unsigned int* probe = (const unsigned int*)P.p[9];   // w3, |x| << 2
    int cnt = 0;
#pragma unroll
    for (int i = 0; i < 64; ++i) {
        unsigned int lo = probe[i] & 0xFFFFu;
        if (((lo >> 7) & 0xFFu) >= 0x80u) ++cnt;
    }
    const bool is_f32 = (cnt > 8);

    const unsigned int* cp = (const unsigned int*)chSrc;
    int z = 0; unsigned int mx = 0;
    for (int i = 0; i < 1024; ++i) {
        unsigned int w = cp[i];
        z += (w == 0u);
        mx = (w > mx) ? w : mx;
    }
    const int chMode = (mx >= 64u) ? 2 : ((z > 300) ? 1 : 0);  // 2=f32, 1=i64, 0=i32

    const int stride = gridDim.x * 256;
    const int gid0 = blockIdx.x * 256 + threadIdx.x;

    const int totalF = P.off[17];
    for (int g = gid0; g < totalF; g += stride) {
        int t = 0;
        while (g >= P.off[t + 1]) ++t;
        int off = g - P.off[t];
        u16 v;
        if (is_f32) v = f2bf(((const float*)P.p[t])[off]);
        else        v = ((const u16*)P.p[t])[off];
        rp[g] = v;
    }
    for (int i = gid0; i < P.chN; i += stride) {
        int v;
        if (chMode == 1)      v = (int)((const long long*)chSrc)[i];
        else if (chMode == 2) v = (int)((const float*)chSrc)[i];
        else                  v = ((const int*)chSrc)[i];
        chi[i] = v & 63;
    }
    for (int i = gid0; i < nU; i += stride) initp[i] = ENC_NINF;
}

// ---- counting sort per batch: points ordered by cluster ----
__global__ __launch_bounds__(256) void k_sort(const int* __restrict__ chi,
                                              int* __restrict__ schoice,
                                              int* __restrict__ perm)
{
    __shared__ int hist[64];
    __shared__ int base[64];
    const int b = blockIdx.x, tid = threadIdx.x;
    if (tid < 64) hist[tid] = 0;
    __syncthreads();
    const int o = b << 13;
    for (int i = tid; i < 8192; i += 256) atomicAdd(&hist[chi[o + i]], 1);
    __syncthreads();
    if (tid == 0) {
        int s = 0;
        for (int k = 0; k < 64; ++k) { base[k] = s; s += hist[k]; }
    }
    __syncthreads();
    for (int i = tid; i < 8192; i += 256) {
        int k = chi[o + i];
        int pos = atomicAdd(&base[k], 1);
        schoice[o + pos] = k;
        perm[o + pos] = o + i;
    }
}

// ---- G1 (NT=2): feat = (relu(bn1(xyz.w1^T+b1))) . w2^T + b2, seg-max fused ----
__global__ __launch_bounds__(256, 2) void g1_feat(
    const u16* __restrict__ xyz, const u16* __restrict__ w1, const u16* __restrict__ b1,
    const u16* __restrict__ g1v, const u16* __restrict__ bb1,
    const u16* __restrict__ m1, const u16* __restrict__ v1,
    const u16* __restrict__ w2, const u16* __restrict__ b2,
    const int* __restrict__ schoice, const int* __restrict__ perm,
    u16* __restrict__ feat, unsigned int* __restrict__ fg_u)
{
    __shared__ __align__(16) u16 Bs[256 * 128];      // 64 KB: both w2 halves
    __shared__ unsigned int lred[8 * 256];           // 8 KB (nk <= 8 fast path)
    __shared__ float4 pw[128];
    __shared__ float xs[128], ys[128], zs[128];
    __shared__ int chs[128];
    const int tid = threadIdx.x, lane = tid & 63, wave = tid >> 6;
    const int wm = (wave & 1) << 6, wn = (wave >> 1) << 6;
    const int m0 = blockIdx.x << 7;
    if (tid < 128) {
        float s = bf2f(g1v[tid]) * rsqrtf(bf2f(v1[tid]) + EPSV);
        float4 w;
        w.x = bf2f(w1[tid * 3 + 0]) * s;
        w.y = bf2f(w1[tid * 3 + 1]) * s;
        w.z = bf2f(w1[tid * 3 + 2]) * s;
        w.w = (bf2f(b1[tid]) - bf2f(m1[tid])) * s + bf2f(bb1[tid]);
        pw[tid] = w;
        const u16* p = xyz + (size_t)perm[m0 + tid] * 3;
        xs[tid] = bf2f(p[0]); ys[tid] = bf2f(p[1]); zs[tid] = bf2f(p[2]);
        chs[tid] = schoice[m0 + tid];
    }
    const int q = lane >> 4, mr = lane & 15;
    f32x4 acc[2][4][4] = {};
#pragma unroll
    for (int i = 0; i < 16; ++i) {
        int id = (i << 8) + tid, row = id >> 4, cc = id & 15;
        async16(w2 + (size_t)row * 128 + ((cc ^ (row & 15)) << 3), &Bs[id << 3]);
    }
    __syncthreads();
    const int kmin = chs[0], nk = chs[127] - kmin + 1;
    const bool useL = (nk <= 8);
    if (useL) for (int i = tid; i < (nk << 8); i += 256) lred[i] = ENC_NINF;
#pragma unroll
    for (int kk = 0; kk < 4; ++kk) {
        const int lc = kk * 4 + q;
        float4 wv[8];
#pragma unroll
        for (int j = 0; j < 8; ++j) wv[j] = pw[kk * 32 + q * 8 + j];
        short8 af[4];
#pragma unroll
        for (int mi = 0; mi < 4; ++mi) {
            int row = wm + mi * 16 + mr;
            float x = xs[row], y = ys[row], z = zs[row];
#pragma unroll
            for (int j = 0; j < 8; ++j) {
                float val = fmaf(x, wv[j].x, fmaf(y, wv[j].y, fmaf(z, wv[j].z, wv[j].w)));
                af[mi][j] = (short)f2bf(fmaxf(val, 0.0f));
            }
        }
#pragma unroll
        for (int h = 0; h < 2; ++h) {
            short8 bfr[4];
#pragma unroll
            for (int ni = 0; ni < 4; ++ni) {
                int r = (h << 7) + wn + ni * 16 + mr;
                bfr[ni] = *(const short8*)&Bs[r * 128 + ((lc ^ (r & 15)) << 3)];
            }
#pragma unroll
            for (int mi = 0; mi < 4; ++mi)
#pragma unroll
                for (int ni = 0; ni < 4; ++ni)
                    acc[h][mi][ni] = __builtin_amdgcn_mfma_f32_16x16x32_bf16(af[mi], bfr[ni], acc[h][mi][ni], 0, 0, 0);
        }
    }
    __syncthreads();
    const int colb = lane & 15;
    const int bl = m0 >> 13;
    unsigned int* db = fg_u + (size_t)(bl << 6) * 256;
#pragma unroll
    for (int h = 0; h < 2; ++h)
#pragma unroll
        for (int ni = 0; ni < 4; ++ni) {
            int n = (h << 7) + wn + (ni << 4) + colb;
            float bv = bf2f(b2[n]);
#pragma unroll
            for (int mi = 0; mi < 4; ++mi) {
                int curk = -1; unsigned int run = 0;
#pragma unroll
                for (int r = 0; r < 4; ++r) {
                    int rr = wm + (mi << 4) + (q << 2) + r;
                    u16 vb = f2bf(acc[h][mi][ni][r] + bv);
                    feat[(size_t)(m0 + rr) * 256 + n] = vb;
                    unsigned int e = encbf(vb);
                    int k = chs[rr];
                    if (k != curk) {
                        if (curk >= 0) {
                            if (useL) atomicMax(&lred[((curk - kmin) << 8) + n], run);
                            else      atomicMax(&db[curk * 256 + n], run);
                        }
                        curk = k; run = e;
                    } else run = run > e ? run : e;
                }
                if (useL) atomicMax(&lred[((curk - kmin) << 8) + n], run);
                else      atomicMax(&db[curk * 256 + n], run);
            }
        }
    if (useL) {
        __syncthreads();
        for (int i = tid; i < (nk << 8); i += 256) {
            unsigned int v = lred[i];
            if (v != ENC_NINF) atomicMax(&db[(kmin + (i >> 8)) * 256 + (i & 255)], v);
        }
    }
}

// ---- G3: h2 = relu(bn2([fg_pts|feat] . w3^T + b3)), NT=2, BK=64 (baseline form,
// proven: VGPR 108 + 128 AGPR acc = 236 total, 0 spill, 0 bank conflicts) ----
__global__ __launch_bounds__(256, 2) void g3_h2(
    const int* __restrict__ schoice, const u16* __restrict__ feat,
    const u16* __restrict__ fg, const u16* __restrict__ w3, const u16* __restrict__ b3,
    const u16* __restrict__ g2, const u16* __restrict__ bb2,
    const u16* __restrict__ m2, const u16* __restrict__ v2,
    u16* __restrict__ h2)
{
    __shared__ __align__(16) u16 As[128 * 64];
    __shared__ __align__(16) u16 Bs[2 * 128 * 64];
    const int tid = threadIdx.x, lane = tid & 63, wave = tid >> 6;
    const int wm = (wave & 1) << 6, wn = (wave >> 1) << 6;
    const int m0 = blockIdx.x << 7, n0 = blockIdx.y << 8;   // 256-wide N group
    const int c = tid & 7, rb = tid >> 3;
    const u16* fgrow[4]; const u16* ftrow[4];
#pragma unroll
    for (int i = 0; i < 4; ++i) {
        int pt = m0 + rb + (i << 5);
        int b = pt >> 13;
        fgrow[i] = fg + (((b << 6) + schoice[pt]) << 8);
        ftrow[i] = feat + ((size_t)pt << 8);
    }
    f32x4 acc[2][4][4] = {};
    for (int k0 = 0; k0 < 512; k0 += 64) {
        __syncthreads();
#pragma unroll
        for (int nt = 0; nt < 2; ++nt)
#pragma unroll
            for (int i = 0; i < 4; ++i) {
                int id = (i << 8) + tid, row = id >> 3, cc = id & 7;
                async16(w3 + (size_t)(n0 + nt * 128 + row) * 512 + k0 + ((cc ^ (row & 7)) << 3),
                        &Bs[nt * 8192 + (id << 3)]);
            }
#pragma unroll
        for (int i = 0; i < 4; ++i) {
            int r = rb + (i << 5);
            int col = k0 + ((c ^ (r & 7)) << 3);
            const u16* src = (col < 256) ? (fgrow[i] + col) : (ftrow[i] + (col - 256));
            async16(src, &As[(((i << 8) + tid) << 3)]);
        }
        __syncthreads();
        const int q = lane >> 4, mr = lane & 15;
#pragma unroll
        for (int kk = 0; kk < 2; ++kk) {
            short8 af[4];
            const int lc = kk * 4 + q;
#pragma unroll
            for (int mi = 0; mi < 4; ++mi) {
                int r = wm + mi * 16 + mr;
                af[mi] = *(const short8*)&As[r * 64 + ((lc ^ (r & 7)) << 3)];
            }
#pragma unroll
            for (int nt = 0; nt < 2; ++nt) {
                short8 bfr[4];
#pragma unroll
                for (int ni = 0; ni < 4; ++ni) {
                    int r = wn + ni * 16 + mr;
                    bfr[ni] = *(const short8*)&Bs[nt * 8192 + r * 64 + ((lc ^ (r & 7)) << 3)];
                }
#pragma unroll
                for (int mi = 0; mi < 4; ++mi)
#pragma unroll
                    for (int ni = 0; ni < 4; ++ni)
                        acc[nt][mi][ni] = __builtin_amdgcn_mfma_f32_16x16x32_bf16(af[mi], bfr[ni], acc[nt][mi][ni], 0, 0, 0);
            }
        }
    }
    const int q = lane >> 4, colb = lane & 15;
#pragma unroll
    for (int nt = 0; nt < 2; ++nt)
#pragma unroll
        for (int ni = 0; ni < 4; ++ni) {
            int n = n0 + nt * 128 + wn + (ni << 4) + colb;
            float s = bf2f(g2[n]) * rsqrtf(bf2f(v2[n]) + EPSV);
            float t = (bf2f(b3[n]) - bf2f(m2[n])) * s + bf2f(bb2[n]);
#pragma unroll
            for (int mi = 0; mi < 4; ++mi)
#pragma unroll
                for (int r = 0; r < 4; ++r) {
                    int m = m0 + wm + (mi << 4) + (q << 2) + r;
                    h2[(size_t)m * 512 + n] = f2bf(fmaxf(fmaf(acc[nt][mi][ni][r], s, t), 0.0f));
                }
        }
}

// ---- G4: out = h2 . w4^T + b4, M=128, FULL N=384, 512 threads, seg-max fused ----
// R5 measured: M=64 version latency-bound (22% occ, 8% HBM, MfmaUtil 17.8%).
// Per-CU L2->LDS staging was 16 blocks x (384KB w4 + 64KB A) = 7.1 MB (~53 us floor).
// B-staging scales 1/M_block -> double M to 128 at 512 threads (8 waves, 2M x 4N,
// wave tile 64x96): per-CU staging halves to ~4 MB, occupancy 22% -> ~50%.
// Register model (validated R5): arch + acc <= 256. acc = 128*384/512 = 96 AGPR,
// arch ~90 (R5 measured 88 for same inner loop) -> ~186, no spill.
// LDS: As 16 KB + Bs 48 KB = 64.5 KB -> 2 blocks/CU.
__global__ __launch_bounds__(512, 2) void g4_out(
    const u16* __restrict__ A, const u16* __restrict__ w4,
    const u16* __restrict__ bias, const int* __restrict__ schoice,
    unsigned int* __restrict__ out_u)
{
    __shared__ __align__(16) u16 smem[32768];        // 64 KB: As(16K) + Bs(48K)
    __shared__ int chs[128];
    u16* As = smem;                                  // 8192 u16
    u16* Bs = smem + 8192;                           // 24576 u16
    const int tid = threadIdx.x, lane = tid & 63, wave = tid >> 6;
    const int wm = (wave & 1) << 6, wn = (wave >> 1) * 96;
    const int m0 = blockIdx.x << 7;
    if (tid < 128) chs[tid] = schoice[m0 + tid];
    f32x4 acc[4][6] = {};
    for (int k0 = 0; k0 < 512; k0 += 64) {
        __syncthreads();
#pragma unroll
        for (int i = 0; i < 6; ++i) {                // w4: 384 rows x 8 chunks
            int id = (i << 9) + tid, row = id >> 3, cc = id & 7;
            async16(w4 + (size_t)row * 512 + k0 + ((cc ^ (row & 7)) << 3),
                    &Bs[id << 3]);
        }
#pragma unroll
        for (int i = 0; i < 2; ++i) {                // h2: 128 rows x 8 chunks
            int id = (i << 9) + tid, row = id >> 3, cc = id & 7;
            async16(A + (size_t)(m0 + row) * 512 + k0 + ((cc ^ (row & 7)) << 3),
                    &As[id << 3]);
        }
        __syncthreads();
        const int q = lane >> 4, mr = lane & 15;
#pragma unroll
        for (int kk = 0; kk < 2; ++kk) {
            const int lc = (kk << 2) + q;
            short8 af[4];
#pragma unroll
            for (int mi = 0; mi < 4; ++mi) {
                int r = wm + (mi << 4) + mr;
                af[mi] = *(const short8*)&As[r * 64 + ((lc ^ (r & 7)) << 3)];
            }
#pragma unroll
            for (int ni = 0; ni < 6; ++ni) {
                int r = wn + (ni << 4) + mr;
                short8 bfr = *(const short8*)&Bs[r * 64 + ((lc ^ (r & 7)) << 3)];
#pragma unroll
                for (int mi = 0; mi < 4; ++mi)
                    acc[mi][ni] = __builtin_amdgcn_mfma_f32_16x16x32_bf16(af[mi], bfr, acc[mi][ni], 0, 0, 0);
            }
        }
    }
    // ---- fused seg-max epilogue ----
    __syncthreads();                                 // staging reads done; reuse smem
    unsigned int* lred = (unsigned int*)smem;        // 16384 u32 capacity
    const int kmin = chs[0], nk = chs[127] - kmin + 1;
    const bool useL = (nk <= 42);                    // nk*384*4 <= 64 KB
    const int bl = m0 >> 13;
    unsigned int* db = out_u + (size_t)(bl << 6) * 384;
    if (useL) for (int i = tid; i < nk * 384; i += 512) lred[i] = ENC_NINF;
    __syncthreads();
    const int q = lane >> 4, colb = lane & 15;
#pragma unroll
    for (int ni = 0; ni < 6; ++ni) {
        int nc = wn + (ni << 4) + colb;
        float bv = bf2f(bias[nc]);
#pragma unroll
        for (int mi = 0; mi < 4; ++mi) {
            int curk = -1; unsigned int run = 0;
#pragma unroll
            for (int r = 0; r < 4; ++r) {
                int rr = wm + (mi << 4) + (q << 2) + r;
                unsigned int e = encbf(f2bf(acc[mi][ni][r] + bv));
                int k = chs[rr];
                if (k != curk) {
                    if (curk >= 0) {
                        if (useL) atomicMax(&lred[(curk - kmin) * 384 + nc], run);
                        else      atomicMax(&db[curk * 384 + nc], run);
                    }
                    curk = k; run = e;
                } else run = run > e ? run : e;
            }
            if (useL) atomicMax(&lred[(curk - kmin) * 384 + nc], run);
            else      atomicMax(&db[curk * 384 + nc], run);
        }
    }
    if (useL) {
        __syncthreads();
        for (int i = tid; i < nk * 384; i += 512) {
            unsigned int v = lred[i];
            if (v != ENC_NINF) {
                int kq = i / 384;
                atomicMax(&db[(kmin + kq) * 384 + (i - kq * 384)], v);
            }
        }
    }
}

__global__ __launch_bounds__(256) void k_dec_bf(const unsigned int* __restrict__ u,
                                                u16* __restrict__ o, int n)
{
    int i = blockIdx.x * 256 + threadIdx.x;
    if (i < n) o[i] = f2bf(dec(u[i]));
}
__global__ __launch_bounds__(256) void k_dec_f32(const unsigned int* __restrict__ u,
                                                 float* __restrict__ o, int n)
{
    int i = blockIdx.x * 256 + threadIdx.x;
    if (i < n) o[i] = dec(u[i]);
}

extern "C" void kernel_launch(void* const* d_in, const int* in_sizes, int n_in,
                              void* d_out, int out_size, void* d_ws, size_t ws_size,
                              hipStream_t stream)
{
    float* out = (float*)d_out;
    if (n_in != 18) {
        k_fillf<<<dim3((out_size + 255) / 256), 256, 0, stream>>>(out, out_size, 1000.0f);
        return;
    }

    const int map[17] = {0, 2, 3, 4, 5, 6, 7, 8, 9, 10, 11, 12, 13, 14, 15, 16, 17};
    Ptrs P;
    P.off[0] = 0;
    for (int i = 0; i < 17; ++i) {
        P.p[i] = d_in[map[i]];
        P.off[i + 1] = P.off[i] + in_sizes[map[i]];
    }
    P.chN = in_sizes[1];

    char* ws = (char*)d_ws;
    int* chi = (int*)ws;
    const size_t chiB = ((size_t)P.chN * 4 + 255) & ~255ull;
    int* schoice = (int*)(ws + chiB);
    int* perm    = (int*)(ws + 2 * chiB);
    u16* rp = (u16*)(ws + 3 * chiB);
    const size_t rpB = ((size_t)P.off[17] * 2 + 255) & ~255ull;
    const size_t RPB = 3 * chiB + rpB;

    // fixed region: fg_u (32*64*256 u32) + out_u (32*64*384 u32) = 5,242,880 B
    unsigned int* fg_u_all  = (unsigned int*)(ws + RPB);
    unsigned int* out_u_all = fg_u_all + 32 * 64 * 256;
    const size_t UB = 5242880ull;
    const int nU = 32 * 64 * 640;

    k_repack<<<dim3(1024), 256, 0, stream>>>(P, d_in[1], chi, rp, fg_u_all, nU);
    k_sort<<<dim3(P.chN >> 13), 256, 0, stream>>>(chi, schoice, perm);

    const u16* xyz  = rp + P.off[0];
    const u16* w1   = rp + P.off[1];
    const u16* b1   = rp + P.off[2];
    const u16* bn1g = rp + P.off[3];
    const u16* bn1b = rp + P.off[4];
    const u16* bn1m = rp + P.off[5];
    const u16* bn1v = rp + P.off[6];
    const u16* w2   = rp + P.off[7];
    const u16* b2   = rp + P.off[8];
    const u16* w3   = rp + P.off[9];
    const u16* b3   = rp + P.off[10];
    const u16* bn2g = rp + P.off[11];
    const u16* bn2b = rp + P.off[12];
    const u16* bn2m = rp + P.off[13];
    const u16* bn2v = rp + P.off[14];
    const u16* w4   = rp + P.off[15];
    const u16* b4   = rp + P.off[16];

    // per-batch: feat 4,194,304 + h2 8,388,608 + fg 32,768 = 12,615,680
    const size_t PB = 12615680ull;
    int sb = 32;
    while (sb > 1 && RPB + UB + (size_t)sb * PB > ws_size) sb >>= 1;
    if (RPB + UB + PB > ws_size) {
        k_fillf<<<dim3((out_size + 255) / 256), 256, 0, stream>>>(out, out_size, 3000.0f);
        return;
    }
    const int ns = 32 / sb;

    char* wsb = ws + RPB + UB;
    const size_t featB = (size_t)sb * 8192 * 256 * 2;
    const size_t h2B   = (size_t)sb * 8192 * 512 * 2;
    u16* feat = (u16*)(wsb);
    u16* h2s  = (u16*)(wsb + featB);
    u16* fg   = (u16*)(wsb + featB + h2B);

    const int mblk = sb << 6;        // 128-row M-tiles (g1, g3, g4)
    const int nfg = sb * 64 * 256;
    const int nou = sb * 64 * 384;
    for (int s = 0; s < ns; ++s) {
        const int b0 = s * sb;
        const int pt0 = b0 << 13;
        const int* sch_sl = schoice + pt0;
        const int* perm_sl = perm + pt0;
        unsigned int* fg_u  = fg_u_all + (size_t)b0 * 64 * 256;
        unsigned int* out_u = out_u_all + (size_t)b0 * 64 * 384;
        g1_feat<<<dim3(mblk), 256, 0, stream>>>(xyz, w1, b1, bn1g, bn1b, bn1m, bn1v,
                                                w2, b2, sch_sl, perm_sl, feat, fg_u);
        k_dec_bf<<<dim3((nfg + 255) / 256), 256, 0, stream>>>(fg_u, fg, nfg);
        g3_h2<<<dim3(mblk, 2), 256, 0, stream>>>(sch_sl, feat, fg, w3, b3,
                                                 bn2g, bn2b, bn2m, bn2v, h2s);
        g4_out<<<dim3(mblk), 512, 0, stream>>>(h2s, w4, b4, sch_sl, out_u);
        k_dec_f32<<<dim3((nou + 255) / 256), 256, 0, stream>>>(out_u,
                                                               out + ((size_t)b0 << 6) * 384, nou);
    }
}